// Round 3
// baseline (42.302 us; speedup 1.0000x reference)
//
#include <hip/hip_runtime.h>

// BPR-style pairwise ranking loss.
// loss = -sum_b sum_{i<j} log_sigmoid((p_i-p_j)(t_i-t_j)) * (t_i-t_j)^2 * m_i*m_j
// With t in {0,1}: only (valid-pos, valid-neg) pairs contribute, each unordered
// pair exactly once, with term log_sigmoid(p_pos - p_neg). So per row:
//   loss_b = -sum_{i in P} sum_{j in N} log_sigmoid(p_i - p_j)
// Base-2 form: log_sigmoid(x) = ln2 * (min(y,0) - log2(1 + 2^-|y|)), y = x*log2e.
//
// Single fused kernel: block b computes partial[b]; the LAST block to finish
// (device-scope counter) reduces all partials and writes out[0]. Agent-scope
// __hip_atomic_* ops give correct visibility across the 8 non-coherent
// per-XCD L2s. The 4-byte counter is zeroed by a hipMemsetAsync node inside
// the captured graph each call; out[0] is bit-deterministic (fixed-order
// final reduce in one block; counter add order is value-irrelevant).

#define BATCH 1024
#define LEN   256
#define LN2f   0.6931471805599453f
#define LOG2Ef 1.4426950408889634f

__global__ __launch_bounds__(256) void bpr_fused_kernel(
    const float* __restrict__ preds,
    const int*   __restrict__ targets,
    const int*   __restrict__ mask,
    float*       __restrict__ partial,   // BATCH floats in ws
    unsigned int* __restrict__ counter,  // 1 uint in ws, zeroed per call
    float*       __restrict__ out)
{
    __shared__ float spos[LEN];     // positives' preds * log2e (compacted)
    __shared__ float sneg[LEN];     // negatives' preds * log2e (compacted)
    __shared__ int   wcp[4], wcn[4];
    __shared__ float wpart[4];
    __shared__ int   is_last;

    const int b    = blockIdx.x;
    const int tid  = threadIdx.x;
    const int wid  = tid >> 6;
    const int lane = tid & 63;

    const float p = preds[b * LEN + tid] * LOG2Ef;
    const int   t = targets[b * LEN + tid];
    const int   m = mask[b * LEN + tid];

    const bool ispos = (m != 0) && (t != 0);
    const bool isneg = (m != 0) && (t == 0);

    const unsigned long long bp = __ballot(ispos);
    const unsigned long long bn = __ballot(isneg);
    if (lane == 0) { wcp[wid] = __popcll(bp); wcn[wid] = __popcll(bn); }
    __syncthreads();

    int opos = 0, oneg = 0;
    for (int w = 0; w < wid; ++w) { opos += wcp[w]; oneg += wcn[w]; }
    const int np = wcp[0] + wcp[1] + wcp[2] + wcp[3];
    const int nn = wcn[0] + wcn[1] + wcn[2] + wcn[3];

    const unsigned long long below = (1ull << lane) - 1ull;
    if (ispos) spos[opos + __popcll(bp & below)] = p;
    if (isneg) sneg[oneg + __popcll(bn & below)] = p;
    __syncthreads();

    // Waves split the negative range (j uniform per wave -> LDS broadcast);
    // lanes stride the positives.
    float acc = 0.0f;
    for (int i = lane; i < np; i += 64) {
        const float yi = spos[i];
        for (int j = wid; j < nn; j += 4) {
            const float y = yi - sneg[j];
            const float e = __builtin_amdgcn_exp2f(-fabsf(y)); // v_exp_f32 -abs
            const float l = __builtin_amdgcn_logf(1.0f + e);   // v_log_f32 (log2)
            acc += fminf(y, 0.0f) - l;
        }
    }

    for (int off = 32; off > 0; off >>= 1)
        acc += __shfl_down(acc, off, 64);
    if (lane == 0) wpart[wid] = acc;
    __syncthreads();

    if (tid == 0) {
        const float bsum = wpart[0] + wpart[1] + wpart[2] + wpart[3];
        __hip_atomic_store(&partial[b], bsum, __ATOMIC_RELEASE,
                           __HIP_MEMORY_SCOPE_AGENT);
        const unsigned int old = __hip_atomic_fetch_add(
            counter, 1u, __ATOMIC_ACQ_REL, __HIP_MEMORY_SCOPE_AGENT);
        is_last = (old == (unsigned int)(gridDim.x - 1)) ? 1 : 0;
    }
    __syncthreads();

    if (is_last) {
        float racc = 0.0f;
        #pragma unroll
        for (int k = tid; k < BATCH; k += 256)
            racc += __hip_atomic_load(&partial[k], __ATOMIC_RELAXED,
                                      __HIP_MEMORY_SCOPE_AGENT);

        for (int off = 32; off > 0; off >>= 1)
            racc += __shfl_down(racc, off, 64);
        if (lane == 0) wpart[wid] = racc;
        __syncthreads();
        if (tid == 0)
            out[0] = -LN2f * (wpart[0] + wpart[1] + wpart[2] + wpart[3]);
    }
}

extern "C" void kernel_launch(void* const* d_in, const int* in_sizes, int n_in,
                              void* d_out, int out_size, void* d_ws, size_t ws_size,
                              hipStream_t stream) {
    const float* preds   = (const float*)d_in[0];
    const int*   targets = (const int*)d_in[1];
    const int*   mask    = (const int*)d_in[2];
    float* out     = (float*)d_out;
    float* partial = (float*)d_ws;                       // BATCH floats
    unsigned int* counter = (unsigned int*)((char*)d_ws + BATCH * sizeof(float));

    hipMemsetAsync(counter, 0, sizeof(unsigned int), stream);
    bpr_fused_kernel<<<BATCH, 256, 0, stream>>>(preds, targets, mask,
                                                partial, counter, out);
}